// Round 7
// baseline (260.849 us; speedup 1.0000x reference)
//
#include <hip/hip_runtime.h>
#include <math.h>

using bf16x8 = __attribute__((ext_vector_type(8))) short;
using f32x4  = __attribute__((ext_vector_type(4))) float;

namespace {
constexpr int kB  = 4;
constexpr int kLQ = 1024;
constexpr int kLK = 2048;
constexpr int kH  = 1024;
constexpr int kHD = 64;
}

__device__ __forceinline__ unsigned short f2bf(float x) {
  union { float f; unsigned int u; } v; v.f = x;
  unsigned int r = v.u + 0x7fffu + ((v.u >> 16) & 1u);   // RNE
  return (unsigned short)(r >> 16);
}

// async global->LDS 16B copy
typedef const __attribute__((address_space(1))) unsigned int guint_t;
typedef __attribute__((address_space(3))) unsigned int luint_t;
__device__ __forceinline__ void g2l16(const void* g, void* l) {
  __builtin_amdgcn_global_load_lds(
      (guint_t*)g,
      (luint_t*)(unsigned int)(unsigned long long)l,
      16, 0, 0);
}

// --------- fused prep: fp32->bf16 casts (q,k,v) + 4 weight transposes --------
__global__ __launch_bounds__(256) void prep_kernel(
    const float* __restrict__ q, const float* __restrict__ k,
    const float* __restrict__ v, const float* __restrict__ Wq,
    const float* __restrict__ Wk, const float* __restrict__ Wv,
    const float* __restrict__ Wo, unsigned short* __restrict__ qo,
    unsigned short* __restrict__ ko, unsigned short* __restrict__ vo,
    unsigned short* __restrict__ WqT, unsigned short* __restrict__ WkT,
    unsigned short* __restrict__ WvT, unsigned short* __restrict__ WoT)
{
  __shared__ float tile[64][65];
  const int t = threadIdx.x;
  if (blockIdx.x < 5632) {
    int c = blockIdx.x * 256 + t;
    const float* src; unsigned short* dst;
    if (c < 393216)      { src = q; dst = qo; }
    else if (c < 917504) { src = k; dst = ko; c -= 393216; }
    else                 { src = v; dst = vo; c -= 917504; }
    const int i = c * 8;
    const float4 a = *(const float4*)(src + i);
    const float4 b = *(const float4*)(src + i + 4);
    uint4 o;
    o.x = (unsigned int)f2bf(a.x) | ((unsigned int)f2bf(a.y) << 16);
    o.y = (unsigned int)f2bf(a.z) | ((unsigned int)f2bf(a.w) << 16);
    o.z = (unsigned int)f2bf(b.x) | ((unsigned int)f2bf(b.y) << 16);
    o.w = (unsigned int)f2bf(b.z) | ((unsigned int)f2bf(b.w) << 16);
    *(uint4*)(dst + i) = o;
    return;
  }
  int id = blockIdx.x - 5632;
  const float* W; unsigned short* Wt; int Kd;
  if (id < 192)      { W = Wq; Wt = WqT; Kd = 768; }
  else if (id < 320) { W = Wk; Wt = WkT; Kd = 512;  id -= 192; }
  else if (id < 448) { W = Wv; Wt = WvT; Kd = 512;  id -= 320; }
  else               { W = Wo; Wt = WoT; Kd = 1024; id -= 448; }
  const int Nd = 1024;
  const int n0 = (id & 15) * 64;
  const int k0 = (id >> 4) * 64;
  const int rr = t >> 4;
  const int c4 = t & 15;
#pragma unroll
  for (int i = 0; i < 4; ++i) {
    const int row = i * 16 + rr;
    const float4 vv = *(const float4*)(W + (size_t)(k0 + row) * Nd + n0 + c4 * 4);
    tile[row][c4*4+0] = vv.x; tile[row][c4*4+1] = vv.y;
    tile[row][c4*4+2] = vv.z; tile[row][c4*4+3] = vv.w;
  }
  __syncthreads();
#pragma unroll
  for (int i = 0; i < 4; ++i) {
    const int n = i * 16 + rr;
    ushort4 o;
    o.x = f2bf(tile[c4*4+0][n]); o.y = f2bf(tile[c4*4+1][n]);
    o.z = f2bf(tile[c4*4+2][n]); o.w = f2bf(tile[c4*4+3][n]);
    *(ushort4*)(Wt + (size_t)(n0 + n) * Kd + k0 + c4 * 4) = o;
  }
}

// ---- 128x256 GEMM body (qkv): BK=32, double-buffered g2l, wave=64x128 -------
// mode 1: bf16 out. mode 2: bf16 out V-transposed.
__device__ __forceinline__ void gemm_body256(
    const unsigned short* __restrict__ A, const unsigned short* __restrict__ Bt,
    const float* __restrict__ bias, unsigned short* __restrict__ Cout,
    int N, int K, int bx, int by, int mode, char* lds)
{
  const int t    = threadIdx.x;
  const int lane = t & 63;
  const int w    = t >> 6;
  const int l15  = lane & 15;
  const int lq8  = (lane >> 4) * 8;
  const int lq4  = (lane >> 4) * 4;
  const int r0   = by * 128;
  const int c0   = bx * 256;
  const int wm   = w >> 1, wn = w & 1;

  f32x4 acc[4][8] = {};

  // prologue: prefetch k0=0 into buffer 0 (24 chunks: A 0..7, B 8..23)
#pragma unroll
  for (int i = 0; i < 6; ++i) {
    const int g = w * 6 + i;
    const unsigned short* src = (g < 8) ? A : Bt;
    const int rbase = (g < 8) ? (r0 + g * 16) : (c0 + (g - 8) * 16);
    g2l16(src + (size_t)(rbase + l15) * K + lq8, lds + g * 1024 + lane * 16);
  }

  int pb = 0;
  for (int k0 = 0; k0 < K; k0 += 32, pb ^= 1) {
    __syncthreads();   // cur buffer drained (issued one compute-phase ago)
    char* buf = lds + pb * 24576;
    if (k0 + 32 < K) {
      char* nbuf = lds + (pb ^ 1) * 24576;
#pragma unroll
      for (int i = 0; i < 6; ++i) {
        const int g = w * 6 + i;
        const unsigned short* src = (g < 8) ? A : Bt;
        const int rbase = (g < 8) ? (r0 + g * 16) : (c0 + (g - 8) * 16);
        g2l16(src + (size_t)(rbase + l15) * K + k0 + 32 + lq8, nbuf + g * 1024 + lane * 16);
      }
    }
    bf16x8 af[4], bfr[8];
#pragma unroll
    for (int i = 0; i < 4; ++i) af[i]  = *(const bf16x8*)(buf + (wm*4 + i) * 1024 + lane * 16);
#pragma unroll
    for (int j = 0; j < 8; ++j) bfr[j] = *(const bf16x8*)(buf + 8192 + (wn*8 + j) * 1024 + lane * 16);
#pragma unroll
    for (int i = 0; i < 4; ++i)
#pragma unroll
      for (int j = 0; j < 8; ++j)
        acc[i][j] = __builtin_amdgcn_mfma_f32_16x16x32_bf16(af[i], bfr[j], acc[i][j], 0, 0, 0);
  }

#pragma unroll
  for (int j = 0; j < 8; ++j) {
    const int col = c0 + wn * 128 + j * 16 + l15;
    const float bcol = bias[col];
#pragma unroll
    for (int i = 0; i < 4; ++i) {
      const int row = r0 + wm * 64 + i * 16 + lq4;
      if (mode == 1) {
#pragma unroll
        for (int r = 0; r < 4; ++r) Cout[(size_t)(row + r) * N + col] = f2bf(acc[i][j][r] + bcol);
      } else {
        const int bb = row >> 11;            // kLK = 2048
        const int lk = row & 2047;
        ushort4 o;
        o.x = f2bf(acc[i][j][0] + bcol); o.y = f2bf(acc[i][j][1] + bcol);
        o.z = f2bf(acc[i][j][2] + bcol); o.w = f2bf(acc[i][j][3] + bcol);
        *(ushort4*)(Cout + (size_t)(bb * kH + col) * kLK + lk) = o;
      }
    }
  }
}

// fused Q/K/V projections: blocks 0..127 Q | 128..383 K | 384..639 V
__global__ __launch_bounds__(256) void qkv_gemm_kernel(
    const unsigned short* __restrict__ qA, const unsigned short* __restrict__ WqT,
    const float* __restrict__ bq, unsigned short* __restrict__ Qb,
    const unsigned short* __restrict__ kA, const unsigned short* __restrict__ WkT,
    const float* __restrict__ bk, unsigned short* __restrict__ Kb,
    const unsigned short* __restrict__ vA, const unsigned short* __restrict__ WvT,
    const float* __restrict__ bv, unsigned short* __restrict__ Vtw)
{
  __shared__ __align__(16) char lds[49152];
  int id = blockIdx.x;
  if (id < 128) {
    gemm_body256(qA, WqT, bq, Qb, 1024, 768, id & 3, id >> 2, 1, lds);
  } else if (id < 384) {
    id -= 128;
    gemm_body256(kA, WkT, bk, Kb, 1024, 512, id & 3, id >> 2, 1, lds);
  } else {
    id -= 384;
    gemm_body256(vA, WvT, bv, Vtw, 1024, 512, id & 3, id >> 2, 2, lds);
  }
}

// out projection: 128x128 tile, BK=32, double-buffered, fp32 out, grid (8,32)
__global__ __launch_bounds__(256) void out_gemm_kernel(
    const unsigned short* __restrict__ A, const unsigned short* __restrict__ Bt,
    const float* __restrict__ bias, float* __restrict__ C)
{
  __shared__ __align__(16) char lds[32768];
  const int t    = threadIdx.x;
  const int lane = t & 63;
  const int w    = t >> 6;
  const int l15  = lane & 15;
  const int lq8  = (lane >> 4) * 8;
  const int lq4  = (lane >> 4) * 4;
  const int r0   = blockIdx.y * 128;
  const int c0   = blockIdx.x * 128;
  const int wm   = w >> 1, wn = w & 1;
  const int N = 1024, K = 1024;

  f32x4 acc[4][4] = {};

#pragma unroll
  for (int i = 0; i < 4; ++i) {
    const int g = w * 4 + i;
    const unsigned short* src = (g < 8) ? A : Bt;
    const int rbase = (g < 8) ? (r0 + g * 16) : (c0 + (g - 8) * 16);
    g2l16(src + (size_t)(rbase + l15) * K + lq8, lds + g * 1024 + lane * 16);
  }
  int pb = 0;
  for (int k0 = 0; k0 < K; k0 += 32, pb ^= 1) {
    __syncthreads();
    char* buf = lds + pb * 16384;
    if (k0 + 32 < K) {
      char* nbuf = lds + (pb ^ 1) * 16384;
#pragma unroll
      for (int i = 0; i < 4; ++i) {
        const int g = w * 4 + i;
        const unsigned short* src = (g < 8) ? A : Bt;
        const int rbase = (g < 8) ? (r0 + g * 16) : (c0 + (g - 8) * 16);
        g2l16(src + (size_t)(rbase + l15) * K + k0 + 32 + lq8, nbuf + g * 1024 + lane * 16);
      }
    }
    bf16x8 af[4], bfr[4];
#pragma unroll
    for (int i = 0; i < 4; ++i) af[i]  = *(const bf16x8*)(buf + (wm*4 + i) * 1024 + lane * 16);
#pragma unroll
    for (int j = 0; j < 4; ++j) bfr[j] = *(const bf16x8*)(buf + 8192 + (wn*4 + j) * 1024 + lane * 16);
#pragma unroll
    for (int i = 0; i < 4; ++i)
#pragma unroll
      for (int j = 0; j < 4; ++j)
        acc[i][j] = __builtin_amdgcn_mfma_f32_16x16x32_bf16(af[i], bfr[j], acc[i][j], 0, 0, 0);
  }
#pragma unroll
  for (int j = 0; j < 4; ++j) {
    const int col = c0 + wn * 64 + j * 16 + l15;
    const float bcol = bias[col];
#pragma unroll
    for (int i = 0; i < 4; ++i) {
      const int row = r0 + wm * 64 + i * 16 + lq4;
#pragma unroll
      for (int r = 0; r < 4; ++r) C[(size_t)(row + r) * N + col] = acc[i][j][r] + bcol;
    }
  }
}

// --------------------- MFMA flash attention (bf16, fp32 acc) -----------------
// Q [B*LQ, H], K [B*LK, H], Vt [B*H, LK], O [B*LQ, H]; all bf16.
// 256 q-rows/block, 4 waves x 64 q-rows; kc-tile = 64. Grid = 256 (1 block/CU),
// flat = qb*64 + bh keeps same-(b,h) blocks on one XCD.
// LDS: K dbuf 2x8K | V single 8K | P 256x72 bf16. Two barriers/iter:
//   A: (PV_{t-1} done) -> issue V_t, K_{t+1}; QK_t; exp; B: (V_t drained) -> PV_t
// MFMA:LDS = 1:1 (64 MFMA vs 24 b128 + 64 b16 per wave-iter).
__global__ __launch_bounds__(256) void attn_mfma_kernel(
    const unsigned short* __restrict__ Q, const unsigned short* __restrict__ K,
    const unsigned short* __restrict__ Vt, unsigned short* __restrict__ O)
{
  __shared__ __align__(16) char lds[61440];
  constexpr int VOFF = 16384;   // V buffer
  constexpr int POFF = 24576;   // P: 256 rows x 72 bf16 (144 B stride)
  const int t    = threadIdx.x;
  const int lane = t & 63;
  const int w    = t >> 6;
  const int l15  = lane & 15;
  const int lq8  = (lane >> 4) * 8;
  const int lq4  = (lane >> 4) * 4;
  const int flat = blockIdx.x;
  const int bh   = flat & 63;
  const int qb   = flat >> 6;
  const int h    = bh & 15;
  const int b    = bh >> 4;
  const int q0   = qb * 256;
  const int hoff = h * kHD;
  const int qw   = w * 64;      // wave's q-row base within block

  // Q fragments: 64 q-rows x 64 d per wave, in registers (32 VGPRs)
  bf16x8 qf[4][2];
#pragma unroll
  for (int qi = 0; qi < 4; ++qi)
#pragma unroll
    for (int kh = 0; kh < 2; ++kh)
      qf[qi][kh] = *(const bf16x8*)(Q + (size_t)(b*kLQ + q0 + qw + qi*16 + l15) * kH
                                      + hoff + kh*32 + lq8);

  f32x4 acc[4][4] = {};
  float lsum[4][4] = {};

  // prologue: prefetch K_0 into Kbuf[0] (8 chunks, 2 per wave)
#pragma unroll
  for (int i = 0; i < 2; ++i) {
    const int g = w * 2 + i;
    g2l16(K + (size_t)(b*kLK + (g >> 1)*16 + l15) * kH + hoff + (g & 1)*32 + lq8,
          lds + g * 1024 + lane * 16);
  }

  for (int kt = 0; kt < kLK / 64; ++kt) {
    const int kc0 = kt * 64;
    char* kbuf = lds + (kt & 1) * 8192;
    __syncthreads();   // (A) PV_{t-1} done with Vbuf & P; K_t present

    // issue V_t (chunks 0..7) and K_{t+1} (chunks 8..15), 3-4 per wave
#pragma unroll
    for (int i = 0; i < 2; ++i) {
      const int gg = w * 2 + i;   // V chunk
      g2l16(Vt + (size_t)(b*kH + hoff + (gg >> 1)*16 + l15) * kLK + kc0 + (gg & 1)*32 + lq8,
            lds + VOFF + gg * 1024 + lane * 16);
    }
    if (kt + 1 < kLK / 64) {
      const int kc1 = kc0 + 64;
      char* nkbuf = lds + ((kt + 1) & 1) * 8192;
#pragma unroll
      for (int i = 0; i < 2; ++i) {
        const int g = w * 2 + i;
        g2l16(K + (size_t)(b*kLK + kc1 + (g >> 1)*16 + l15) * kH + hoff + (g & 1)*32 + lq8,
              nkbuf + g * 1024 + lane * 16);
      }
    }

    // S = Q K^T : 64 q-rows x 64 kc per wave (32 MFMA, K-frags reused 4x)
    f32x4 s[4][4];
#pragma unroll
    for (int kcf = 0; kcf < 4; ++kcf) {
      const bf16x8 kf0 = *(const bf16x8*)(kbuf + (kcf*2 + 0) * 1024 + lane * 16);
      const bf16x8 kf1 = *(const bf16x8*)(kbuf + (kcf*2 + 1) * 1024 + lane * 16);
#pragma unroll
      for (int qi = 0; qi < 4; ++qi) {
        f32x4 z = {};
        z = __builtin_amdgcn_mfma_f32_16x16x32_bf16(qf[qi][0], kf0, z, 0, 0, 0);
        z = __builtin_amdgcn_mfma_f32_16x16x32_bf16(qf[qi][1], kf1, z, 0, 0, 0);
        s[qi][kcf] = z;
      }
    }

    // P = exp2(s*log2e/8); bf16 truncation store (bias cancels via norm)
#pragma unroll
    for (int qi = 0; qi < 4; ++qi)
#pragma unroll
      for (int kcf = 0; kcf < 4; ++kcf)
#pragma unroll
        for (int r = 0; r < 4; ++r) {
          const float p = __builtin_amdgcn_exp2f(s[qi][kcf][r] * 0.18033688011112042f);
          lsum[qi][r] += p;
          union { float f; unsigned int u; } pu; pu.f = p;
          *(unsigned short*)(lds + POFF +
              ((qw + qi*16 + lq4 + r) * 72 + kcf*16 + l15) * 2) =
              (unsigned short)(pu.u >> 16);
        }

    __syncthreads();   // (B) drains V_t (and K_{t+1}); P rows are wave-private

    // O += P V : 32 MFMA (V-frags reused 4x across qi)
    bf16x8 pf[4][2];
#pragma unroll
    for (int qi = 0; qi < 4; ++qi)
#pragma unroll
      for (int kq = 0; kq < 2; ++kq)
        pf[qi][kq] = *(const bf16x8*)(lds + POFF +
            ((qw + qi*16 + l15) * 72 + kq*32 + lq8) * 2);
#pragma unroll
    for (int vd = 0; vd < 4; ++vd) {
      const bf16x8 vf0 = *(const bf16x8*)(lds + VOFF + (vd*2 + 0) * 1024 + lane * 16);
      const bf16x8 vf1 = *(const bf16x8*)(lds + VOFF + (vd*2 + 1) * 1024 + lane * 16);
#pragma unroll
      for (int qi = 0; qi < 4; ++qi) {
        acc[qi][vd] = __builtin_amdgcn_mfma_f32_16x16x32_bf16(pf[qi][0], vf0, acc[qi][vd], 0, 0, 0);
        acc[qi][vd] = __builtin_amdgcn_mfma_f32_16x16x32_bf16(pf[qi][1], vf1, acc[qi][vd], 0, 0, 0);
      }
    }
  }

  // reduce row sums across the 16 lanes sharing each row quad
#pragma unroll
  for (int qi = 0; qi < 4; ++qi)
#pragma unroll
    for (int r = 0; r < 4; ++r) {
      float v = lsum[qi][r];
      v += __shfl_xor(v, 1);
      v += __shfl_xor(v, 2);
      v += __shfl_xor(v, 4);
      v += __shfl_xor(v, 8);
      lsum[qi][r] = 1.f / v;
    }
#pragma unroll
  for (int qi = 0; qi < 4; ++qi)
#pragma unroll
    for (int vd = 0; vd < 4; ++vd)
#pragma unroll
      for (int r = 0; r < 4; ++r)
        O[(size_t)(b*kLQ + q0 + qw + qi*16 + lq4 + r) * kH + hoff + vd*16 + l15] =
            f2bf(acc[qi][vd][r] * lsum[qi][r]);
}

extern "C" void kernel_launch(void* const* d_in, const int* in_sizes, int n_in,
                              void* d_out, int out_size, void* d_ws, size_t ws_size,
                              hipStream_t stream) {
  (void)in_sizes; (void)n_in; (void)out_size; (void)ws_size;
  const float* query = (const float*)d_in[0];
  const float* key   = (const float*)d_in[1];
  const float* value = (const float*)d_in[2];
  const float* Wq = (const float*)d_in[3];
  const float* bq = (const float*)d_in[4];
  const float* Wk = (const float*)d_in[5];
  const float* bk = (const float*)d_in[6];
  const float* Wv = (const float*)d_in[7];
  const float* bv = (const float*)d_in[8];
  const float* Wo = (const float*)d_in[9];
  const float* bo = (const float*)d_in[10];
  float* out = (float*)d_out;

  unsigned short* ws  = (unsigned short*)d_ws;
  unsigned short* qA  = ws;                  // 4*1024*768
  unsigned short* kA  = qA  + 3145728;       // 4*2048*512
  unsigned short* vA  = kA  + 4194304;
  unsigned short* WqT = vA  + 4194304;       // 1024*768
  unsigned short* WkT = WqT + 786432;        // 1024*512
  unsigned short* WvT = WkT + 524288;
  unsigned short* WoT = WvT + 524288;        // 1024*1024
  unsigned short* Qb  = WoT + 1048576;       // 4096*1024
  unsigned short* Kb  = Qb  + 4194304;       // 8192*1024
  unsigned short* Vtw = Kb  + 8388608;       // 4096*2048 (transposed V)
  unsigned short* Ab  = Vtw + 8388608;       // 4096*1024

  dim3 blk(256);
  prep_kernel<<<6336, blk, 0, stream>>>(query, key, value, Wq, Wk, Wv, Wo,
                                        qA, kA, vA, WqT, WkT, WvT, WoT);
  qkv_gemm_kernel<<<640, blk, 0, stream>>>(qA, WqT, bq, Qb,
                                           kA, WkT, bk, Kb,
                                           vA, WvT, bv, Vtw);
  attn_mfma_kernel<<<256, blk, 0, stream>>>(Qb, Kb, Vtw, Ab);
  out_gemm_kernel<<<dim3(8, 32), blk, 0, stream>>>(Ab, WoT, bo, out);
}